// Round 5
// baseline (187.212 us; speedup 1.0000x reference)
//
#include <hip/hip_runtime.h>
#include <hip/hip_bf16.h>

// out[e] = relu(concat(x[src],x[dst]) @ W1 + b1) @ W2 + b2
// Phase 1: uv[n][0:256] = x[n]@W1[:256,:], uv[n][256:512] = x[n]@W1[256:,:]  (bf16)
//   Barrier-free streaming GEMM: each wave holds a 64-col slice of W1 entirely
//   in registers (128 VGPR) and streams 16-row chunks of x.
// Phase 2: per-edge sum_k relu(uv[src][k]+uv[dst][256+k]+b1[k])*W2[k] + b2.

typedef short short8 __attribute__((ext_vector_type(8)));
typedef float f32x4 __attribute__((ext_vector_type(4)));

#define DINC 256
#define NOUTC 512

__device__ inline unsigned short f2bf(float f) {   // RNE (cold paths)
  union { float f; unsigned u; } c; c.f = f;
  unsigned u = c.u;
  return (unsigned short)((u + 0x7FFFu + ((u >> 16) & 1u)) >> 16);
}
__device__ inline float bf2f(unsigned short h) {
  union { unsigned u; float f; } c; c.u = ((unsigned)h) << 16;
  return c.f;
}
// Hot-path cvt: scalar cast -> compiler fuses pairs to v_cvt_pk_bf16_f32 (m240)
__device__ inline unsigned short fbf(float f) {
  union { __hip_bfloat16 h; unsigned short u; } c;
  c.h = __float2bfloat16(f);
  return c.u;
}

// W1t[j][k] = bf16(W1'[k][j]); j<256 -> u-half (W1 rows 0..255), j>=256 -> v-half.
__global__ void w1t_kernel(const float* __restrict__ W1, unsigned short* __restrict__ W1t) {
  int t = blockIdx.x * 256 + threadIdx.x;           // 0..131071
  int j = t >> 8, k = t & 255;
  float v = W1[(size_t)(k + ((j >= 256) ? 256 : 0)) * DINC + (j & 255)];
  W1t[(size_t)j * DINC + k] = f2bf(v);
}

// 256 thr = 4 waves. Wave gw: col-slice s = gw&7 (64 cols), row-stream gw>>3.
// B slice in registers: breg[kf][nf] (8*4 short8 = 128 VGPR), loaded once.
// Per 16-row chunk: 16 dense fp32 dwordx4 loads -> cvt -> 32 MFMA -> 4 stores.
// No LDS, no barriers: waves free-run; latency hidden by in-flight loads + TLP.
__global__ __launch_bounds__(256, 2) void uv_gemm(const float* __restrict__ x,
                                                  const unsigned short* __restrict__ W1t,
                                                  unsigned short* __restrict__ uv,
                                                  int Nn) {
  // Block->XCD is round-robin (b%8). Remap so logical blocks are contiguous per
  // XCD: the 2 logical blocks (8 waves) sharing one row-stream then share an L2.
  int bpx = gridDim.x >> 3;                          // blocks per XCD (grid % 8 == 0)
  int L = (blockIdx.x & 7) * bpx + (blockIdx.x >> 3);

  int lane = threadIdx.x & 63;
  int lr = lane & 15, kg = lane >> 4;
  int gw = L * 4 + (threadIdx.x >> 6);               // global logical wave id
  int s = gw & 7;                                    // col slice: cols s*64..s*64+63
  int n0 = s * 64;
  int stream = gw >> 3;
  int nstreams = (gridDim.x * 4) >> 3;

  // ---- B slice -> registers (once, from L2-resident W1t) ----
  short8 breg[8][4];
#pragma unroll
  for (int kf = 0; kf < 8; ++kf)
#pragma unroll
    for (int nf = 0; nf < 4; ++nf)
      breg[kf][nf] = *(const short8*)(W1t + (size_t)(n0 + nf * 16 + lr) * DINC +
                                      kf * 32 + kg * 8);

  int nch = (Nn + 15) >> 4;                          // 16-row chunks (6250)

  for (int c = stream; c < nch; c += nstreams) {
    int row = c * 16 + lr;
    int rrow = row < Nn ? row : Nn - 1;              // clamp reads; stores guarded
    const float4* xp = (const float4*)(x + (size_t)rrow * DINC + kg * 8);

    f32x4 acc[4] = {};
#pragma unroll
    for (int kf = 0; kf < 8; ++kf) {
      float4 f0 = xp[kf * 8];
      float4 f1 = xp[kf * 8 + 1];
      short8 a;
      a[0] = (short)fbf(f0.x); a[1] = (short)fbf(f0.y);
      a[2] = (short)fbf(f0.z); a[3] = (short)fbf(f0.w);
      a[4] = (short)fbf(f1.x); a[5] = (short)fbf(f1.y);
      a[6] = (short)fbf(f1.z); a[7] = (short)fbf(f1.w);
#pragma unroll
      for (int nf = 0; nf < 4; ++nf)
        acc[nf] = __builtin_amdgcn_mfma_f32_16x16x32_bf16(breg[kf][nf], a,
                                                          acc[nf], 0, 0, 0);
    }

    // Swapped-operand C/D: lane = row (lr), cols n0+nf*16+kg*4+(0..3) -> 8B stores
    if (row < Nn) {
      unsigned short* orow = uv + (size_t)row * NOUTC + n0 + kg * 4;
#pragma unroll
      for (int nf = 0; nf < 4; ++nf) {
        ushort4 pk;
        pk.x = fbf(acc[nf][0]);
        pk.y = fbf(acc[nf][1]);
        pk.z = fbf(acc[nf][2]);
        pk.w = fbf(acc[nf][3]);
        *(ushort4*)(orow + nf * 16) = pk;
      }
    }
  }
}

// Quarter-wave (16 lanes) per edge: lane owns 16 of 256 channels.
__global__ __launch_bounds__(256) void edge_kernel(const int* __restrict__ eliW,
                                                   const unsigned short* __restrict__ uv,
                                                   const float* __restrict__ b1,
                                                   const float* __restrict__ W2,
                                                   const float* __restrict__ b2,
                                                   float* __restrict__ out, int E) {
  int tid = threadIdx.x;
  int ql = tid & 15;
  bool is64 = ((eliW[1] | eliW[3] | eliW[5] | eliW[7] | eliW[9] | eliW[11]) == 0);
  int shift = is64 ? 1 : 0;

  float bl[16], wl[16];
  *(float4*)(bl + 0)  = *(const float4*)(b1 + ql * 8);
  *(float4*)(bl + 4)  = *(const float4*)(b1 + ql * 8 + 4);
  *(float4*)(bl + 8)  = *(const float4*)(b1 + 128 + ql * 8);
  *(float4*)(bl + 12) = *(const float4*)(b1 + 128 + ql * 8 + 4);
  *(float4*)(wl + 0)  = *(const float4*)(W2 + ql * 8);
  *(float4*)(wl + 4)  = *(const float4*)(W2 + ql * 8 + 4);
  *(float4*)(wl + 8)  = *(const float4*)(W2 + 128 + ql * 8);
  *(float4*)(wl + 12) = *(const float4*)(W2 + 128 + ql * 8 + 4);
  float bias2 = b2[0];

  int qid = (blockIdx.x * blockDim.x + tid) >> 4;
  int nq = (gridDim.x * blockDim.x) >> 4;

  for (int e = qid; e < E; e += nq) {
    int src = eliW[((size_t)e) << shift];
    int dst = eliW[((size_t)(E + e)) << shift];
    const unsigned short* up = uv + (size_t)src * NOUTC;
    const unsigned short* vp = uv + (size_t)dst * NOUTC + DINC;
    short8 uu[2], vv[2];
    uu[0] = *(const short8*)(up + ql * 8);
    uu[1] = *(const short8*)(up + 128 + ql * 8);
    vv[0] = *(const short8*)(vp + ql * 8);
    vv[1] = *(const short8*)(vp + 128 + ql * 8);
    float s = 0.f;
#pragma unroll
    for (int g = 0; g < 2; ++g)
#pragma unroll
      for (int j = 0; j < 8; ++j) {
        float h = bf2f((unsigned short)uu[g][j]) + bf2f((unsigned short)vv[g][j]) + bl[g * 8 + j];
        s += fmaxf(h, 0.f) * wl[g * 8 + j];
      }
#pragma unroll
    for (int off = 8; off; off >>= 1) s += __shfl_xor(s, off, 64);
    if (ql == 0) out[e] = s + bias2;
  }
}

extern "C" void kernel_launch(void* const* d_in, const int* in_sizes, int n_in,
                              void* d_out, int out_size, void* d_ws, size_t ws_size,
                              hipStream_t stream) {
  const float* x   = (const float*)d_in[0];
  const int*   eli = (const int*)d_in[1];
  const float* W1  = (const float*)d_in[2];
  const float* b1  = (const float*)d_in[3];
  const float* W2  = (const float*)d_in[4];
  const float* b2  = (const float*)d_in[5];
  float* out = (float*)d_out;

  int Nn = in_sizes[0] / DINC;     // 100000
  int E  = in_sizes[1] / 2;        // 500000

  unsigned short* W1t = (unsigned short*)d_ws;              // 512*256*2 = 256 KB
  unsigned short* uv  = W1t + (size_t)NOUTC * DINC;         // Nn*512*2 ~ 102.4 MB

  w1t_kernel<<<512, 256, 0, stream>>>(W1, W1t);

  // 512 blocks x 4 waves = 2048 waves: 8 col-slices x 256 row-streams,
  // 2 blocks/CU (launch_bounds(256,2)).
  uv_gemm<<<512, 256, 0, stream>>>(x, W1t, uv, Nn);

  edge_kernel<<<2048, 256, 0, stream>>>(eli, uv, b1, W2, b2, out, E);
}